// Round 7
// baseline (1644.224 us; speedup 1.0000x reference)
//
#include <hip/hip_runtime.h>
#include <math.h>

// Problem constants (from reference)
#define TT 2048
#define BB 512
#define II 11
#define HH 33
#define NL 3
#define OO 18
#define HSLOT 48          // halves per LDS vector slot (96 B, 16B-aligned slots)

typedef _Float16 h4 __attribute__((ext_vector_type(4)));
typedef _Float16 h8 __attribute__((ext_vector_type(8)));   // 16 B -> ds_read_b128

// fast sigmoid / tanh via v_exp_f32 + v_rcp_f32 (saturate correctly at +-inf)
__device__ __forceinline__ float sigm_f(float x) {
    float e = __expf(-x);
    return __builtin_amdgcn_rcpf(1.0f + e);
}
__device__ __forceinline__ float tanh_f(float x) {
    float e = __expf(2.0f * x);
    return 1.0f - 2.0f * __builtin_amdgcn_rcpf(e + 1.0f);
}

// DPP quad_perm [1,0,3,2]: exchange within adjacent lane pairs (VALU pipe, no LDS)
__device__ __forceinline__ float dpp_xor1(float v) {
    return __builtin_bit_cast(float,
        __builtin_amdgcn_update_dpp(0, __builtin_bit_cast(int, v), 0xB1, 0xF, 0xF, true));
}

// guarded fp32->fp16 row-slice loads (zero-pad past rem)
__device__ __forceinline__ h8 gldh8(const float* p, int k0, int rem) {
    h8 v;
    #pragma unroll
    for (int i = 0; i < 8; ++i) v[i] = (_Float16)((k0 + i < rem) ? p[k0 + i] : 0.0f);
    return v;
}
__device__ __forceinline__ h4 gldh4(const float* p, int k0, int rem) {
    h4 v;
    #pragma unroll
    for (int i = 0; i < 4; ++i) v[i] = (_Float16)((k0 + i < rem) ? p[k0 + i] : 0.0f);
    return v;
}

// v_dot2_f32_f16 chains: 2 MACs/op, fp32 accumulate
#define D8(a, v, w) do { \
    a = __builtin_amdgcn_fdot2((v).s01, (w).s01, a, false); \
    a = __builtin_amdgcn_fdot2((v).s23, (w).s23, a, false); \
    a = __builtin_amdgcn_fdot2((v).s45, (w).s45, a, false); \
    a = __builtin_amdgcn_fdot2((v).s67, (w).s67, a, false); } while (0)
#define D4(a, v, w) do { \
    a = __builtin_amdgcn_fdot2((v).s01, (w).s01, a, false); \
    a = __builtin_amdgcn_fdot2((v).s23, (w).s23, a, false); } while (0)

// Layer-pipelined LSTM, PAIR-per-unit role-split, fp16 fdot2, TWO batch
// elements per lane (same unit/role -> weights shared, misc amortized).
// grid = 256 blocks (2 batch elements each), block = 256 threads (4 waves).
//   tid < 198 : u = tid>>1 (unit 0..98), p = tid&1 (role). l = u/33, j = u%33.
//     Role p=0: reads the layer INPUT vector (slot l), holds the 4 W_ih rows.
//     Role p=1: reads the OWN-h vector (slot l+1), holds the 4 W_hh rows.
//     Each lane runs the full gate pipeline for BOTH elements (c0, c1) —
//     two independent dependency chains give in-wave ILP (we are down to
//     1 wave/SIMD, so ILP must replace TLP for latency hiding).
//   Pair all-reduce via DPP; activation dedupe via tanh(x)=2*sigm(2x)-1.
//   tid 198..219 : x prefetchers (2 elems x 11 features), 2-deep pipeline.
// LDS: ping-pong buf[2][elem][4][HSLOT] halves; one barrier per superstep.
// __launch_bounds__(256,1): 512-VGPR slack -> ~150 working regs stay true VGPRs.
__global__ __launch_bounds__(256, 1) void lstm_pipeline_kernel(
    const float* __restrict__ x,
    const float* __restrict__ Wih0, const float* __restrict__ Whh0,
    const float* __restrict__ bih0, const float* __restrict__ bhh0,
    const float* __restrict__ Wih1, const float* __restrict__ Whh1,
    const float* __restrict__ bih1, const float* __restrict__ bhh1,
    const float* __restrict__ Wih2, const float* __restrict__ Whh2,
    const float* __restrict__ bih2, const float* __restrict__ bhh2,
    float* __restrict__ hidden_out)   // [3, 512, 33]
{
    __shared__ __align__(16) _Float16 buf[2][2][NL + 1][HSLOT];  // [ping][elem][slot][48]

    const int tid = threadIdx.x;
    const int bg0 = blockIdx.x * 2;

    for (int i = tid; i < 2 * 2 * (NL + 1) * HSLOT; i += 256)
        ((_Float16*)buf)[i] = (_Float16)0.0f;

    const bool comp = (tid < 198);
    const int  u    = tid >> 1;          // unit 0..98
    const int  p    = tid & 1;           // 0 = input-role, 1 = h-role
    const int  l    = (u < 33) ? 0 : (u < 66) ? 1 : 2;
    const int  j    = u - 33 * l;

    const int  pr   = tid - 198;         // 0..21 prefetch roles
    const bool pref = (pr >= 0) && (pr < 2 * II);
    const int  pe   = pref ? (pr / II) : 0;   // which elem
    const int  pf   = pref ? (pr % II) : 0;   // which feature
    const float* xrow = x + (size_t)(bg0 + pe) * TT * II + pf;

    // ---- per-lane weights: 4 gate rows x 36 cols, packed fp16 = 72 VGPRs ----
    h8 z8 = {0,0,0,0,0,0,0,0};
    h4 z4 = {0,0,0,0};
    h8 w0a=z8,w0b=z8,w0c=z8,w0d=z8; h4 w0t=z4;   // gate i
    h8 w1a=z8,w1b=z8,w1c=z8,w1d=z8; h4 w1t=z4;   // gate f
    h8 w2a=z8,w2b=z8,w2c=z8,w2d=z8; h4 w2t=z4;   // gate g
    h8 w3a=z8,w3b=z8,w3c=z8,w3d=z8; h4 w3t=z4;   // gate o
    float b0 = 0.0f, b1 = 0.0f, b2 = 0.0f, b3 = 0.0f;

    if (comp) {
        const float* bip = (l == 0) ? bih0 : (l == 1) ? bih1 : bih2;
        const float* bhp = (l == 0) ? bhh0 : (l == 1) ? bhh1 : bhh2;
        if (p == 0) {   // bias once per pair; the all-reduce restores both lanes
            b0 = bip[0 * HH + j] + bhp[0 * HH + j];
            b1 = bip[1 * HH + j] + bhp[1 * HH + j];
            b2 = bip[2 * HH + j] + bhp[2 * HH + j];
            b3 = bip[3 * HH + j] + bhp[3 * HH + j];
        }
        const float* Wsrc = p ? ((l == 0) ? Whh0 : (l == 1) ? Whh1 : Whh2)
                              : ((l == 0) ? Wih0 : (l == 1) ? Wih1 : Wih2);
        const int kin = (p || l != 0) ? HH : II;
        const float* r0 = Wsrc + (0 * HH + j) * kin;
        const float* r1 = Wsrc + (1 * HH + j) * kin;
        const float* r2 = Wsrc + (2 * HH + j) * kin;
        const float* r3 = Wsrc + (3 * HH + j) * kin;
        w0a = gldh8(r0, 0, kin); w0b = gldh8(r0, 8, kin);
        w0c = gldh8(r0, 16, kin); w0d = gldh8(r0, 24, kin); w0t = gldh4(r0, 32, kin);
        w1a = gldh8(r1, 0, kin); w1b = gldh8(r1, 8, kin);
        w1c = gldh8(r1, 16, kin); w1d = gldh8(r1, 24, kin); w1t = gldh4(r1, 32, kin);
        w2a = gldh8(r2, 0, kin); w2b = gldh8(r2, 8, kin);
        w2c = gldh8(r2, 16, kin); w2d = gldh8(r2, 24, kin); w2t = gldh4(r2, 32, kin);
        w3a = gldh8(r3, 0, kin); w3b = gldh8(r3, 8, kin);
        w3c = gldh8(r3, 16, kin); w3d = gldh8(r3, 24, kin); w3t = gldh4(r3, 32, kin);
    }

    __syncthreads();
    float v_next = 0.0f, v_next2 = 0.0f;
    if (pref) {
        buf[0][pe][0][pf] = (_Float16)xrow[0];
        v_next  = xrow[II];
        v_next2 = xrow[2 * II];
    }
    __syncthreads();

    float c0e = 0.0f, c1e = 0.0f;            // cell state, elem 0 / elem 1
    const int   vsel = p ? (l + 1) : l;      // which LDS slot this lane reads
    const float mA   = 1.0f + (float)p;      // activation-a: 1 -> sigm, 2 -> tanh
    const float cAc  = -(float)p;

    // full gate pipeline for one element; returns new h (valid in both lanes)
    auto unit_step = [&](const _Float16* V16, float& c) -> float {
        const h8* V = (const h8*)V16;
        const h8 v0 = V[0], v1 = V[1], v2 = V[2], v3 = V[3];
        const h4 vt = *(const h4*)(V16 + 32);

        float a0 = b0, a1 = b1, a2 = b2, a3 = b3;
        D8(a0, v0, w0a); D8(a1, v0, w1a); D8(a2, v0, w2a); D8(a3, v0, w3a);
        D8(a0, v1, w0b); D8(a1, v1, w1b); D8(a2, v1, w2b); D8(a3, v1, w3b);
        D8(a0, v2, w0c); D8(a1, v2, w1c); D8(a2, v2, w2c); D8(a3, v2, w3c);
        D8(a0, v3, w0d); D8(a1, v3, w1d); D8(a2, v3, w2d); D8(a3, v3, w3d);
        D4(a0, vt, w0t); D4(a1, vt, w1t); D4(a2, vt, w2t); D4(a3, vt, w3t);

        a0 += dpp_xor1(a0); a1 += dpp_xor1(a1);
        a2 += dpp_xor1(a2); a3 += dpp_xor1(a3);

        // p0 activates i,f; p1 activates g,o (tanh via 2*sigm(2x)-1)
        const float aA = p ? a2 : a0;
        const float aB = p ? a3 : a1;
        const float acta = __builtin_fmaf(mA, sigm_f(mA * aA), cAc); // i or g
        const float actb = sigm_f(aB);                               // f or o
        const float xa = dpp_xor1(acta);
        const float xb = dpp_xor1(actb);
        const float ig = p ? xa : acta;
        const float gg = p ? acta : xa;
        const float fg = p ? xb : actb;
        const float og = p ? actb : xb;

        c = __builtin_fmaf(fg, c, ig * gg);   // identical in both lanes (fp32)
        return og * tanh_f(c);
    };

    for (int s = 0; s < TT + NL - 1; ++s) {
        const int rp = s & 1;
        const int wp = rp ^ 1;

        if (pref) {
            if (s + 1 < TT) buf[wp][pe][0][pf] = (_Float16)v_next;  // 2-step vmcnt slack
            v_next = v_next2;
            if (s + 3 < TT) v_next2 = xrow[(size_t)(s + 3) * II];
        }

        const bool active = comp && (s >= l) && (s - l < TT);
        if (active) {
            const float hA = unit_step(&buf[rp][0][vsel][0], c0e);
            const float hB = unit_step(&buf[rp][1][vsel][0], c1e);

            if (p == 0) {
                buf[wp][0][l + 1][j] = (_Float16)hA;
                buf[wp][1][l + 1][j] = (_Float16)hB;
                if (s - l == TT - 1) {
                    hidden_out[((size_t)l * BB + bg0 + 0) * HH + j] = hA;
                    hidden_out[((size_t)l * BB + bg0 + 1) * HH + j] = hB;
                }
            }
        }

        __syncthreads();
    }
}

// MLP head: hidden [3*512, 33] -> gelu(hidden@W1^T + b1) [.,72] -> @W2^T + b2 [.,18]
__global__ void mlp_head_kernel(const float* __restrict__ hidden,
                                const float* __restrict__ W1, const float* __restrict__ b1,
                                const float* __restrict__ W2, const float* __restrict__ b2,
                                float* __restrict__ out)
{
    const int row = blockIdx.x * blockDim.x + threadIdx.x;   // 0..1535
    if (row >= NL * BB) return;

    float hv[HH];
    #pragma unroll
    for (int k = 0; k < HH; ++k) hv[k] = hidden[row * HH + k];

    float h1[4 * OO];
    #pragma unroll
    for (int m = 0; m < 4 * OO; ++m) {
        float a = b1[m];
        #pragma unroll
        for (int k = 0; k < HH; ++k) a += hv[k] * W1[m * HH + k];
        h1[m] = 0.5f * a * (1.0f + erff(a * 0.70710678118654752f));
    }
    #pragma unroll
    for (int o = 0; o < OO; ++o) {
        float a = b2[o];
        #pragma unroll
        for (int m = 0; m < 4 * OO; ++m) a += h1[m] * W2[o * (4 * OO) + m];
        out[row * OO + o] = a;
    }
}

extern "C" void kernel_launch(void* const* d_in, const int* in_sizes, int n_in,
                              void* d_out, int out_size, void* d_ws, size_t ws_size,
                              hipStream_t stream) {
    const float* x    = (const float*)d_in[0];
    const float* Wih0 = (const float*)d_in[1];
    const float* Whh0 = (const float*)d_in[2];
    const float* bih0 = (const float*)d_in[3];
    const float* bhh0 = (const float*)d_in[4];
    const float* Wih1 = (const float*)d_in[5];
    const float* Whh1 = (const float*)d_in[6];
    const float* bih1 = (const float*)d_in[7];
    const float* bhh1 = (const float*)d_in[8];
    const float* Wih2 = (const float*)d_in[9];
    const float* Whh2 = (const float*)d_in[10];
    const float* bih2 = (const float*)d_in[11];
    const float* bhh2 = (const float*)d_in[12];
    const float* W1   = (const float*)d_in[13];
    const float* b1   = (const float*)d_in[14];
    const float* W2   = (const float*)d_in[15];
    const float* b2   = (const float*)d_in[16];

    float* out    = (float*)d_out;                 // [3,512,18] = 27648 floats
    float* hidden = out + NL * BB * OO;            // [3,512,33] = 50688 floats

    lstm_pipeline_kernel<<<BB / 2, 256, 0, stream>>>(
        x, Wih0, Whh0, bih0, bhh0, Wih1, Whh1, bih1, bhh1,
        Wih2, Whh2, bih2, bhh2, hidden);

    mlp_head_kernel<<<(NL * BB + 255) / 256, 256, 0, stream>>>(
        hidden, W1, b1, W2, b2, out);
}